// Round 6
// baseline (14599.539 us; speedup 1.0000x reference)
//
#include <hip/hip_runtime.h>

// ============================================================================
// GRUTimeSeries (B=256,T=512,H=512,OUT=256) — round 6: persistent cooperative
// kernel, round-5-verified math, standards-based agent-scope acq/rel barrier.
// 192 blocks (3 roles x 64), 512 thr, 96KB LDS weights staged once.
//   L0 (bid 0..63):   h0(t)   = GRU0(h0(t-1), x(t))          t in [0,512)
//   GX (bid 64..127): gx1(t-1)= Wih1 @ h0(t-1)               t in [1,512]
//   GH (bid 128..191): h1(t-2)= GRU1(h1(t-3), gx1(t-2))      t in [2,513]
// One grid barrier per tick (release fetch_add -> block0 -> release gen).
// h published f16 (== round-5 numerics), recurrent state fp32 in registers,
// gx1 exchanged fp32. Predicted absmax == round 5's 0.00390625 exactly.
// ============================================================================

#define NTH 512

typedef __attribute__((ext_vector_type(8))) _Float16 f16x8;
typedef __attribute__((ext_vector_type(4))) float f32x4;

__device__ __forceinline__ unsigned short f2h(float f) {
  union { _Float16 h; unsigned short u; } v; v.h = (_Float16)f;
  return v.u;
}
__device__ __forceinline__ float sig_(float v) { return 1.0f / (1.0f + expf(-v)); }

__global__ __launch_bounds__(256) void ws_zero_v5(unsigned* __restrict__ p) {
  // zero h0b+h1b: 1 MiB = 262144 dwords
  int i = blockIdx.x * 256 + threadIdx.x;
  for (; i < 262144; i += gridDim.x * 256) p[i] = 0u;
}

__global__ __launch_bounds__(NTH, 1) void gru_persist(
    const float* __restrict__ x,
    const float* __restrict__ Wih0, const float* __restrict__ Whh0,
    const float* __restrict__ bih0, const float* __restrict__ bhh0,
    const float* __restrict__ Wih1, const float* __restrict__ Whh1,
    const float* __restrict__ bih1, const float* __restrict__ bhh1,
    char* __restrict__ ws, float* __restrict__ h1f)
{
  extern __shared__ char lds[];  // 96 rows x 1024B f16 weights, swizzled

  unsigned* cnt = (unsigned*)ws;                     // 8 counters, 64B stride
  unsigned* gen = (unsigned*)(ws + 512);             // generation broadcast
  unsigned short* h0b = (unsigned short*)(ws + 4096);          // 2 slots f16
  unsigned short* h1b = h0b + 2 * 131072;                      // 2 slots f16
  float* gxb = (float*)(ws + 1052672);               // [2][64 rb][64][96] f32

  const int tid = threadIdx.x;
  const int wv = tid >> 6, lane = tid & 63, l15 = lane & 15, q = lane >> 4;
  const int bid = blockIdx.x;
  const int role = bid >> 6;          // 0=L0, 1=GX, 2=GH
  const int rb = bid & 63;
  const int bt = rb & 3, dt = rb >> 2;
  const int rg = wv >> 1;             // row-group (16 rows each)
  const int hh = wv & 1;              // N-half (16 dims each)
  const int row0 = bt * 64 + rg * 16; // this wave's batch rows
  const int dim = dt * 32 + hh * 16 + l15;
  const int swl = (l15 & 7) << 4;

  // ---- stage this role's weight matrix, f16, XOR-swizzled (round-5 scheme)
  {
    const float* Wsrc = role == 0 ? Whh0 : (role == 1 ? Wih1 : Whh1);
    for (int u = tid; u < 96 * 64; u += NTH) {
      const int r = u >> 6, c8 = u & 63;
      const int g3 = r >> 5, dd = r & 31;
      const float* src = Wsrc + (size_t)((g3 << 9) + dt * 32 + dd) * 512 + (c8 << 3);
      const float4 v0 = *(const float4*)src;
      const float4 v1 = *(const float4*)(src + 4);
      f16x8 hv;
      hv[0] = (_Float16)v0.x; hv[1] = (_Float16)v0.y;
      hv[2] = (_Float16)v0.z; hv[3] = (_Float16)v0.w;
      hv[4] = (_Float16)v1.x; hv[5] = (_Float16)v1.y;
      hv[6] = (_Float16)v1.z; hv[7] = (_Float16)v1.w;
      *(f16x8*)(lds + (r << 10) + ((c8 ^ (r & 7)) << 4)) = hv;
    }
  }

  // ---- per-lane scalar constants
  float c0w[3], c0i[3], c0h[3], c1i[3], c1h[3];
  if (role == 0) {
    #pragma unroll
    for (int g3 = 0; g3 < 3; ++g3) {
      c0w[g3] = Wih0[(g3 << 9) + dim];
      c0i[g3] = bih0[(g3 << 9) + dim];
      c0h[g3] = bhh0[(g3 << 9) + dim];
    }
  } else if (role == 2) {
    #pragma unroll
    for (int g3 = 0; g3 < 3; ++g3) {
      c1i[g3] = bih1[(g3 << 9) + dim];
      c1h[g3] = bhh1[(g3 << 9) + dim];
    }
  }

  float hst[4];
  #pragma unroll
  for (int j = 0; j < 4; ++j) hst[j] = 0.f;

  __syncthreads();  // weights visible block-wide (h zeroed by prior kernel)

  for (int t = 0; t <= 513; ++t) {
    const bool act = (role == 0) ? (t < 512)
                   : (role == 1) ? (t >= 1 && t <= 512)
                                 : (t >= 2);
    f32x4 acc[3];
    #pragma unroll
    for (int g3 = 0; g3 < 3; ++g3) acc[g3] = (f32x4){0.f, 0.f, 0.f, 0.f};

    if (act) {
      // A operand: roles 0,1 read h0(t-1); role 2 reads h1(t-3). slot (t+1)&1.
      const unsigned short* hsrc =
          (role == 2 ? h1b : h0b) + (size_t)((t + 1) & 1) * 131072;
      const unsigned short* ap = hsrc + (size_t)(row0 + l15) * 512 + (q << 3);
      #pragma unroll
      for (int half = 0; half < 2; ++half) {
        f16x8 af[8];
        #pragma unroll
        for (int kc2 = 0; kc2 < 8; ++kc2)
          af[kc2] = *(const f16x8*)(ap + (half * 8 + kc2) * 32);
        #pragma unroll
        for (int kc2 = 0; kc2 < 8; ++kc2) {
          const int kc = half * 8 + kc2;
          const int bb = ((kc << 6) + (q << 4)) ^ swl;
          #pragma unroll
          for (int g3 = 0; g3 < 3; ++g3) {
            const f16x8 bf = *(const f16x8*)(lds + (((g3 << 5) + (hh << 4) + l15) << 10) + bb);
            acc[g3] = __builtin_amdgcn_mfma_f32_16x16x32_f16(af[kc2], bf, acc[g3], 0, 0, 0);
          }
        }
      }
    }

    if (act) {
      if (role == 0) {            // layer-0 gate math, publish h0(t) f16
        unsigned short* hdst = h0b + (size_t)(t & 1) * 131072;
        #pragma unroll
        for (int j = 0; j < 4; ++j) {
          const int row = row0 + q * 4 + j;
          const float xv = x[(size_t)row * 512 + t];
          const float r = sig_(xv * c0w[0] + c0i[0] + acc[0][j] + c0h[0]);
          const float z = sig_(xv * c0w[1] + c0i[1] + acc[1][j] + c0h[1]);
          const float n = tanhf(xv * c0w[2] + c0i[2] + r * (acc[2][j] + c0h[2]));
          const float h = (1.f - z) * n + z * hst[j];
          hst[j] = h;
          hdst[(size_t)row * 512 + dim] = f2h(h);
        }
      } else if (role == 1) {     // publish raw gx1(t-1) fp32, slot (t-1)&1
        float* gxc = gxb + (size_t)(((t + 1) & 1) * 64 + rb) * 6144;
        #pragma unroll
        for (int g3 = 0; g3 < 3; ++g3)
          #pragma unroll
          for (int j = 0; j < 4; ++j)
            gxc[(rg * 16 + q * 4 + j) * 96 + (g3 << 5) + (hh << 4) + l15] = acc[g3][j];
      } else {                    // layer-1 gate math for s=t-2, publish h1(s)
        const float* gxc = gxb + (size_t)((t & 1) * 64 + rb) * 6144;  // slot s&1
        unsigned short* hdst = h1b + (size_t)(t & 1) * 131072;        // slot s&1
        #pragma unroll
        for (int j = 0; j < 4; ++j) {
          const int rr = rg * 16 + q * 4 + j;
          const float gxr = gxc[rr * 96 + (hh << 4) + l15];
          const float gxz = gxc[rr * 96 + 32 + (hh << 4) + l15];
          const float gxn = gxc[rr * 96 + 64 + (hh << 4) + l15];
          const float r = sig_(gxr + c1i[0] + acc[0][j] + c1h[0]);
          const float z = sig_(gxz + c1i[1] + acc[1][j] + c1h[1]);
          const float n = tanhf(gxn + c1i[2] + r * (acc[2][j] + c1h[2]));
          const float h = (1.f - z) * n + z * hst[j];
          hst[j] = h;
          const int row = row0 + q * 4 + j;
          hdst[(size_t)row * 512 + dim] = f2h(h);
          if (t == 513) h1f[(size_t)row * 512 + dim] = h;
        }
      }
    }

    // ---- grid barrier: release-add -> block0 gathers -> release gen
    __syncthreads();
    if (tid == 0) {
      __hip_atomic_fetch_add(&cnt[(bid & 7) << 4], 1u,
                             __ATOMIC_RELEASE, __HIP_MEMORY_SCOPE_AGENT);
      const unsigned tgt = 24u * (unsigned)(t + 1);
      if (bid == 0) {
        for (int i = 0; i < 8; ++i)
          while (__hip_atomic_load(&cnt[i << 4], __ATOMIC_ACQUIRE,
                                   __HIP_MEMORY_SCOPE_AGENT) < tgt)
            __builtin_amdgcn_s_sleep(2);
        __hip_atomic_store(gen, (unsigned)(t + 1),
                           __ATOMIC_RELEASE, __HIP_MEMORY_SCOPE_AGENT);
      } else {
        while (__hip_atomic_load(gen, __ATOMIC_ACQUIRE,
                                 __HIP_MEMORY_SCOPE_AGENT) < (unsigned)(t + 1))
          __builtin_amdgcn_s_sleep(2);
      }
    }
    __syncthreads();
    __builtin_amdgcn_sched_barrier(0);
  }
}

// ---------------- fp32 MLP head: Y[b,j] = act(sum_k X[b,k]*W[j,k] + bias[j])
__global__ __launch_bounds__(256)
void mlp_head_v5(const float* __restrict__ X, const float* __restrict__ W,
                 const float* __restrict__ bias, float* __restrict__ Y,
                 const int N, const int act)
{
  __shared__ float Xs[32][258];
  __shared__ float Ws[8][260];
  const int tid = threadIdx.x;
  const int m0 = blockIdx.x << 5;
  const int j0 = blockIdx.y << 6;
  const int b  = tid >> 3;
  const int jj = tid & 7;
  float acc[8];
  #pragma unroll
  for (int i = 0; i < 8; ++i) acc[i] = 0.f;
  for (int kh = 0; kh < 2; ++kh) {
    __syncthreads();
    for (int u = tid; u < 2048; u += 256) {
      const int row = u >> 6, c4 = u & 63;
      const float4 v = *((const float4*)(X + ((m0 + row) << 9) + (kh << 8)) + c4);
      float* dst = &Xs[row][c4 << 2];
      dst[0] = v.x; dst[1] = v.y; dst[2] = v.z; dst[3] = v.w;
    }
    __syncthreads();
    #pragma unroll
    for (int jg = 0; jg < 8; ++jg) {
      if (jg) __syncthreads();
      for (int u = tid; u < 512; u += 256) {
        const int row = u >> 6, c4 = u & 63;
        const float4 v = *((const float4*)(W + ((j0 + (jg << 3) + row) << 9) + (kh << 8)) + c4);
        float* dst = &Ws[row][c4 << 2];
        dst[0] = v.x; dst[1] = v.y; dst[2] = v.z; dst[3] = v.w;
      }
      __syncthreads();
      float a = 0.f;
      #pragma unroll 8
      for (int k = 0; k < 256; ++k) a += Xs[b][k] * Ws[jj][k];
      acc[jg] += a;
    }
  }
  #pragma unroll
  for (int jg = 0; jg < 8; ++jg) {
    const int j = j0 + (jg << 3) + jj;
    float v = acc[jg] + bias[j];
    v = act ? (1.f / (1.f + __expf(-v))) : fmaxf(v, 0.f);
    Y[(m0 + b) * N + j] = v;
  }
}

extern "C" void kernel_launch(void* const* d_in, const int* in_sizes, int n_in,
                              void* d_out, int out_size, void* d_ws, size_t ws_size,
                              hipStream_t stream) {
  (void)in_sizes; (void)n_in; (void)out_size; (void)ws_size;
  const float* x    = (const float*)d_in[0];
  const float* Wih0 = (const float*)d_in[1];
  const float* Whh0 = (const float*)d_in[2];
  const float* bih0 = (const float*)d_in[3];
  const float* bhh0 = (const float*)d_in[4];
  const float* Wih1 = (const float*)d_in[5];
  const float* Whh1 = (const float*)d_in[6];
  const float* bih1 = (const float*)d_in[7];
  const float* bhh1 = (const float*)d_in[8];
  const float* W1 = (const float*)d_in[9];
  const float* b1 = (const float*)d_in[10];
  const float* W2 = (const float*)d_in[11];
  const float* b2 = (const float*)d_in[12];
  const float* W3 = (const float*)d_in[13];
  const float* b3 = (const float*)d_in[14];

  char* ws = (char*)d_ws;
  // layout: [0,4096) barrier | h0b 512K | h1b 512K @4096.. | gx 3M @1052672
  //         | h1f 512K @4198400 | y1 @4722688 | y2 @5246976  (total ~5.7 MiB)
  float* h1f = (float*)(ws + 4198400);
  float* y1  = (float*)(ws + 4722688);
  float* y2  = (float*)(ws + 5246976);

  hipMemsetAsync(ws, 0, 4096, stream);                 // barrier counters
  ws_zero_v5<<<64, 256, 0, stream>>>((unsigned*)(ws + 4096));  // h slots

  hipFuncSetAttribute((const void*)gru_persist,
                      hipFuncAttributeMaxDynamicSharedMemorySize, 98304);

  void* args[11];
  args[0] = &x;    args[1] = &Wih0; args[2] = &Whh0; args[3] = &bih0;
  args[4] = &bhh0; args[5] = &Wih1; args[6] = &Whh1; args[7] = &bih1;
  args[8] = &bhh1; args[9] = &ws;   args[10] = &h1f;
  hipLaunchCooperativeKernel((const void*)gru_persist, dim3(192), dim3(NTH),
                             args, 98304, stream);

  mlp_head_v5<<<dim3(8, 8), 256, 0, stream>>>(h1f, W1, b1, y1, 512, 0);
  mlp_head_v5<<<dim3(8, 8), 256, 0, stream>>>(y1, W2, b2, y2, 512, 0);
  mlp_head_v5<<<dim3(8, 4), 256, 0, stream>>>(y2, W3, b3, (float*)d_out, 256, 1);
}